// Round 1
// baseline (2099.819 us; speedup 1.0000x reference)
//
#include <hip/hip_runtime.h>

// ---------------- types & helpers ----------------
typedef short short8 __attribute__((ext_vector_type(8)));
typedef float f32x4 __attribute__((ext_vector_type(4)));

#define MFMA_BF16(a, b, c) __builtin_amdgcn_mfma_f32_16x16x32_bf16((a), (b), (c), 0, 0, 0)

__device__ __forceinline__ float bf2f(unsigned short u) {
    return __uint_as_float(((unsigned)u) << 16);
}
__device__ __forceinline__ unsigned short f2bf(float f) {
    unsigned u = __float_as_uint(f);
    u += 0x7FFFu + ((u >> 16) & 1u);  // round-to-nearest-even
    return (unsigned short)(u >> 16);
}
__device__ __forceinline__ float sigm(float x) { return 1.0f / (1.0f + __expf(-x)); }
__device__ __forceinline__ float tanh_(float x) {
    float e = __expf(-2.0f * fabsf(x));
    float t = (1.0f - e) / (1.0f + e);
    return copysignf(t, x);
}

#define NROW 6144
#define HD   256
#define G4   1024
#define TT   30

// ---------------- weight conversion / packing ----------------
// regions: W_hid 65536 | W_ih0[:, :256] 262144 | W_hh0 262144 | Wcat1=[W_ih1|W_hh1] 524288
__global__ __launch_bounds__(256) void cvt_weights(
    const float* __restrict__ W_hid, const float* __restrict__ W_ih0,
    const float* __restrict__ W_hh0, const float* __restrict__ W_ih1,
    const float* __restrict__ W_hh1,
    unsigned short* __restrict__ Whid_b, unsigned short* __restrict__ Wih0_b,
    unsigned short* __restrict__ Whh0_b, unsigned short* __restrict__ Wcat1_b)
{
    int idx = blockIdx.x * 256 + threadIdx.x;
    if (idx < 65536) { Whid_b[idx] = f2bf(W_hid[idx]); return; }
    idx -= 65536;
    if (idx < 262144) {
        int gc = idx >> 8, k = idx & 255;
        Wih0_b[idx] = f2bf(W_ih0[gc * 258 + k]);
        return;
    }
    idx -= 262144;
    if (idx < 262144) { Whh0_b[idx] = f2bf(W_hh0[idx]); return; }
    idx -= 262144;
    if (idx < 524288) {
        int gc = idx >> 9, k = idx & 511;
        float v = (k < 256) ? W_ih1[gc * 256 + k] : W_hh1[gc * 256 + (k - 256)];
        Wcat1_b[idx] = f2bf(v);
    }
}

// combined[n, c] : c<128 obs[b], c<192 lane[b], else ds[kk]
__global__ __launch_bounds__(256) void build_combined(
    const float* __restrict__ obs, const float* __restrict__ lane,
    const float* __restrict__ ds, unsigned short* __restrict__ comb)
{
    int idx = blockIdx.x * 256 + threadIdx.x;  // < 6144*256
    int n = idx >> 8, c = idx & 255;
    int b = n / 6, kk = n - b * 6;
    float v;
    if (c < 128)      v = obs[b * 128 + c];
    else if (c < 192) v = lane[b * 64 + (c - 128)];
    else              v = ds[kk * 64 + (c - 192)];
    comb[idx] = f2bf(v);
}

// ---------------- GEMM: hidden = leakyrelu(combined @ W_hid^T + b_hid) ----------------
// block: 4 waves; block tile 64 rows x 256 cols; wave w: cols [w*64, w*64+64)
__global__ __launch_bounds__(256) void gemm_hidden(
    const unsigned short* __restrict__ A, const unsigned short* __restrict__ B,
    const float* __restrict__ b_hid, unsigned short* __restrict__ hidden)
{
    int wid = threadIdx.x >> 6, lane = threadIdx.x & 63;
    int lrow = lane & 15, kg = lane >> 4;
    int r0 = blockIdx.x * 64;
    int c0 = wid * 64;
    f32x4 acc[4][4];
#pragma unroll
    for (int i = 0; i < 4; i++)
#pragma unroll
        for (int j = 0; j < 4; j++) acc[i][j] = f32x4{0.f, 0.f, 0.f, 0.f};

#pragma unroll
    for (int kb = 0; kb < 256; kb += 32) {
        int k = kb + kg * 8;
        short8 a[4], b[4];
#pragma unroll
        for (int mi = 0; mi < 4; mi++)
            a[mi] = *(const short8*)(A + (size_t)(r0 + mi * 16 + lrow) * 256 + k);
#pragma unroll
        for (int ni = 0; ni < 4; ni++)
            b[ni] = *(const short8*)(B + (size_t)(c0 + ni * 16 + lrow) * 256 + k);
#pragma unroll
        for (int mi = 0; mi < 4; mi++)
#pragma unroll
            for (int ni = 0; ni < 4; ni++)
                acc[mi][ni] = MFMA_BF16(a[mi], b[ni], acc[mi][ni]);
    }
#pragma unroll
    for (int mi = 0; mi < 4; mi++) {
#pragma unroll
        for (int ni = 0; ni < 4; ni++) {
            int col = c0 + ni * 16 + lrow;
            float bb = b_hid[col];
#pragma unroll
            for (int r = 0; r < 4; r++) {
                int row = r0 + mi * 16 + kg * 4 + r;
                float x = acc[mi][ni][r] + bb;
                x = x >= 0.f ? x : 0.1f * x;
                hidden[(size_t)row * 256 + col] = f2bf(x);
            }
        }
    }
}

// ---------------- endpoint / conf head (thread per row) ----------------
__global__ __launch_bounds__(256) void head_kernel(
    const unsigned short* __restrict__ hidden, const float* __restrict__ W_ep,
    const float* __restrict__ b_ep, const float* __restrict__ W_conf,
    const float* __restrict__ b_conf, float* __restrict__ out_conf,
    float* __restrict__ out_ep, float* __restrict__ ep_buf)
{
    int n = blockIdx.x * 256 + threadIdx.x;  // < 6144
    const unsigned short* hr = hidden + (size_t)n * 256;
    float e0 = 0.f, e1 = 0.f, cf = 0.f;
    for (int k = 0; k < 256; k += 8) {
        short8 hv = *(const short8*)(hr + k);
#pragma unroll
        for (int i = 0; i < 8; i++) {
            float h = bf2f((unsigned short)hv[i]);
            e0 += h * W_ep[k + i];
            e1 += h * W_ep[256 + k + i];
            cf += h * W_conf[k + i];
        }
    }
    e0 += b_ep[0]; e1 += b_ep[1]; cf += b_conf[0];
    out_conf[n] = cf;
    out_ep[2 * n] = e0; out_ep[2 * n + 1] = e1;
    ep_buf[2 * n] = e0; ep_buf[2 * n + 1] = e1;
}

// ---------------- GEMM: gx0 = dec_in @ W_ih0^T + b_ih0 ----------------
// A = hidden (bf16), rank-2 endpoint correction in epilogue.
__global__ __launch_bounds__(256) void gemm_gx0(
    const unsigned short* __restrict__ A, const unsigned short* __restrict__ B,
    const float* __restrict__ W_ih0f, const float* __restrict__ b_ih0,
    const float* __restrict__ ep_buf, float* __restrict__ gx0)
{
    int wid = threadIdx.x >> 6, lane = threadIdx.x & 63;
    int lrow = lane & 15, kg = lane >> 4;
    int r0 = blockIdx.x * 64;
    int c0 = blockIdx.y * 256 + wid * 64;
    f32x4 acc[4][4];
#pragma unroll
    for (int i = 0; i < 4; i++)
#pragma unroll
        for (int j = 0; j < 4; j++) acc[i][j] = f32x4{0.f, 0.f, 0.f, 0.f};

#pragma unroll
    for (int kb = 0; kb < 256; kb += 32) {
        int k = kb + kg * 8;
        short8 a[4], b[4];
#pragma unroll
        for (int mi = 0; mi < 4; mi++)
            a[mi] = *(const short8*)(A + (size_t)(r0 + mi * 16 + lrow) * 256 + k);
#pragma unroll
        for (int ni = 0; ni < 4; ni++)
            b[ni] = *(const short8*)(B + (size_t)(c0 + ni * 16 + lrow) * 256 + k);
#pragma unroll
        for (int mi = 0; mi < 4; mi++)
#pragma unroll
            for (int ni = 0; ni < 4; ni++)
                acc[mi][ni] = MFMA_BF16(a[mi], b[ni], acc[mi][ni]);
    }
#pragma unroll
    for (int mi = 0; mi < 4; mi++) {
#pragma unroll
        for (int ni = 0; ni < 4; ni++) {
            int gc = c0 + ni * 16 + lrow;
            float w256 = W_ih0f[(size_t)gc * 258 + 256];
            float w257 = W_ih0f[(size_t)gc * 258 + 257];
            float bb = b_ih0[gc];
#pragma unroll
            for (int r = 0; r < 4; r++) {
                int row = r0 + mi * 16 + kg * 4 + r;
                float e0 = ep_buf[2 * row], e1 = ep_buf[2 * row + 1];
                gx0[(size_t)row * 1024 + gc] = acc[mi][ni][r] + bb + e0 * w256 + e1 * w257;
            }
        }
    }
}

// ---------------- LSTM layer 0 step ----------------
// block tile: 64 rows x 64 jcols (x 4 gates); wave w: jcols [j0+w*16, +16)
__global__ __launch_bounds__(256) void lstm_step0(
    const unsigned short* __restrict__ h_in, const unsigned short* __restrict__ Whh0_b,
    const float* __restrict__ gx0, const float* __restrict__ b_hh0,
    float* __restrict__ c0, unsigned short* __restrict__ h_out)
{
    int wid = threadIdx.x >> 6, lane = threadIdx.x & 63;
    int lrow = lane & 15, kg = lane >> 4;
    int r0 = blockIdx.x * 64;
    int j0 = blockIdx.y * 64 + wid * 16;
    f32x4 acc[4][4];  // [mi][gate]
#pragma unroll
    for (int i = 0; i < 4; i++)
#pragma unroll
        for (int j = 0; j < 4; j++) acc[i][j] = f32x4{0.f, 0.f, 0.f, 0.f};

#pragma unroll
    for (int kb = 0; kb < 256; kb += 32) {
        int k = kb + kg * 8;
        short8 a[4], b[4];
#pragma unroll
        for (int mi = 0; mi < 4; mi++)
            a[mi] = *(const short8*)(h_in + (size_t)(r0 + mi * 16 + lrow) * 256 + k);
#pragma unroll
        for (int g = 0; g < 4; g++)
            b[g] = *(const short8*)(Whh0_b + (size_t)((g << 8) + j0 + lrow) * 256 + k);
#pragma unroll
        for (int mi = 0; mi < 4; mi++)
#pragma unroll
            for (int g = 0; g < 4; g++)
                acc[mi][g] = MFMA_BF16(a[mi], b[g], acc[mi][g]);
    }
    int jc = j0 + lrow;
    float bi = b_hh0[jc], bf_ = b_hh0[256 + jc], bg = b_hh0[512 + jc], bo = b_hh0[768 + jc];
#pragma unroll
    for (int mi = 0; mi < 4; mi++) {
#pragma unroll
        for (int r = 0; r < 4; r++) {
            int row = r0 + mi * 16 + kg * 4 + r;
            const float* gxr = gx0 + (size_t)row * 1024 + jc;
            float gi = acc[mi][0][r] + gxr[0] + bi;
            float gf = acc[mi][1][r] + gxr[256] + bf_;
            float gg = acc[mi][2][r] + gxr[512] + bg;
            float go = acc[mi][3][r] + gxr[768] + bo;
            size_t ci = (size_t)row * 256 + jc;
            float cn = sigm(gf) * c0[ci] + sigm(gi) * tanh_(gg);
            float hn = sigm(go) * tanh_(cn);
            c0[ci] = cn;
            h_out[ci] = f2bf(hn);
        }
    }
}

// ---------------- LSTM layer 1 step (fused input proj + cell + prev-step out proj) ----------------
__global__ __launch_bounds__(256) void lstm_step1(
    const unsigned short* __restrict__ h0n, const unsigned short* __restrict__ h1p,
    const unsigned short* __restrict__ Wcat1_b, const float* __restrict__ b_ih1,
    const float* __restrict__ b_hh1, const float* __restrict__ W_op,
    const float* __restrict__ b_op, float* __restrict__ c1,
    unsigned short* __restrict__ h_out, float* __restrict__ out_final, int t)
{
    int wid = threadIdx.x >> 6, lane = threadIdx.x & 63;
    int lrow = lane & 15, kg = lane >> 4;
    int r0 = blockIdx.x * 64;
    int j0 = blockIdx.y * 64 + wid * 16;
    bool doproj = (blockIdx.y == 0) && (wid == 0) && (t > 0);
    f32x4 acc[4][4];
#pragma unroll
    for (int i = 0; i < 4; i++)
#pragma unroll
        for (int j = 0; j < 4; j++) acc[i][j] = f32x4{0.f, 0.f, 0.f, 0.f};
    float po0[4] = {0.f, 0.f, 0.f, 0.f}, po1[4] = {0.f, 0.f, 0.f, 0.f};

#pragma unroll
    for (int kb = 0; kb < 512; kb += 32) {
        int k = kb + kg * 8;
        const unsigned short* Abase = (kb < 256) ? h0n : h1p;
        int kk = (kb < 256) ? k : (k - 256);
        short8 a[4], b[4];
#pragma unroll
        for (int mi = 0; mi < 4; mi++)
            a[mi] = *(const short8*)(Abase + (size_t)(r0 + mi * 16 + lrow) * 256 + kk);
#pragma unroll
        for (int g = 0; g < 4; g++)
            b[g] = *(const short8*)(Wcat1_b + (size_t)((g << 8) + j0 + lrow) * 512 + k);
#pragma unroll
        for (int mi = 0; mi < 4; mi++)
#pragma unroll
            for (int g = 0; g < 4; g++)
                acc[mi][g] = MFMA_BF16(a[mi], b[g], acc[mi][g]);
        if (kb >= 256 && doproj) {
            int kw = k - 256;
            f32x4 w0a = *(const f32x4*)(W_op + kw);
            f32x4 w0b = *(const f32x4*)(W_op + kw + 4);
            f32x4 w1a = *(const f32x4*)(W_op + 256 + kw);
            f32x4 w1b = *(const f32x4*)(W_op + 256 + kw + 4);
#pragma unroll
            for (int mi = 0; mi < 4; mi++) {
#pragma unroll
                for (int i = 0; i < 8; i++) {
                    float hv = bf2f((unsigned short)a[mi][i]);
                    float w0 = (i < 4) ? w0a[i] : w0b[i - 4];
                    float w1 = (i < 4) ? w1a[i] : w1b[i - 4];
                    po0[mi] += hv * w0;
                    po1[mi] += hv * w1;
                }
            }
        }
    }
    int jc = j0 + lrow;
    float bi = b_ih1[jc] + b_hh1[jc];
    float bf_ = b_ih1[256 + jc] + b_hh1[256 + jc];
    float bg = b_ih1[512 + jc] + b_hh1[512 + jc];
    float bo = b_ih1[768 + jc] + b_hh1[768 + jc];
#pragma unroll
    for (int mi = 0; mi < 4; mi++) {
#pragma unroll
        for (int r = 0; r < 4; r++) {
            int row = r0 + mi * 16 + kg * 4 + r;
            float gi = acc[mi][0][r] + bi;
            float gf = acc[mi][1][r] + bf_;
            float gg = acc[mi][2][r] + bg;
            float go = acc[mi][3][r] + bo;
            size_t ci = (size_t)row * 256 + jc;
            float cn = sigm(gf) * c1[ci] + sigm(gi) * tanh_(gg);
            float hn = sigm(go) * tanh_(cn);
            c1[ci] = cn;
            h_out[ci] = f2bf(hn);
        }
    }
    if (doproj) {
        float bo0 = b_op[0], bo1 = b_op[1];
#pragma unroll
        for (int mi = 0; mi < 4; mi++) {
            float s0 = po0[mi];
            s0 += __shfl_xor(s0, 16, 64);
            s0 += __shfl_xor(s0, 32, 64);
            float s1 = po1[mi];
            s1 += __shfl_xor(s1, 16, 64);
            s1 += __shfl_xor(s1, 32, 64);
            if (kg == 0) {
                int row = r0 + mi * 16 + lrow;
                out_final[(size_t)(row * TT + (t - 1)) * 2 + 0] = s0 + bo0;
                out_final[(size_t)(row * TT + (t - 1)) * 2 + 1] = s1 + bo1;
            }
        }
    }
}

// ---------------- final step output projection ----------------
__global__ __launch_bounds__(256) void final_proj(
    const unsigned short* __restrict__ h1, const float* __restrict__ W_op,
    const float* __restrict__ b_op, float* __restrict__ out_final)
{
    int n = blockIdx.x * 256 + threadIdx.x;  // < 6144
    const unsigned short* hr = h1 + (size_t)n * 256;
    float p0 = 0.f, p1 = 0.f;
    for (int k = 0; k < 256; k += 8) {
        short8 hv = *(const short8*)(hr + k);
#pragma unroll
        for (int i = 0; i < 8; i++) {
            float h = bf2f((unsigned short)hv[i]);
            p0 += h * W_op[k + i];
            p1 += h * W_op[256 + k + i];
        }
    }
    out_final[(size_t)(n * TT + (TT - 1)) * 2 + 0] = p0 + b_op[0];
    out_final[(size_t)(n * TT + (TT - 1)) * 2 + 1] = p1 + b_op[1];
}

// ---------------- host ----------------
extern "C" void kernel_launch(void* const* d_in, const int* in_sizes, int n_in,
                              void* d_out, int out_size, void* d_ws, size_t ws_size,
                              hipStream_t stream)
{
    const float* obs    = (const float*)d_in[0];
    const float* lane   = (const float*)d_in[1];
    const float* ds     = (const float*)d_in[3];
    const float* W_hid  = (const float*)d_in[4];
    const float* b_hid  = (const float*)d_in[5];
    const float* W_ep   = (const float*)d_in[6];
    const float* b_ep   = (const float*)d_in[7];
    const float* W_conf = (const float*)d_in[8];
    const float* b_conf = (const float*)d_in[9];
    const float* W_ih0  = (const float*)d_in[10];
    const float* W_hh0  = (const float*)d_in[11];
    const float* b_ih0  = (const float*)d_in[12];
    const float* b_hh0  = (const float*)d_in[13];
    const float* W_ih1  = (const float*)d_in[14];
    const float* W_hh1  = (const float*)d_in[15];
    const float* b_ih1  = (const float*)d_in[16];
    const float* b_hh1  = (const float*)d_in[17];
    const float* W_op   = (const float*)d_in[18];
    const float* b_op   = (const float*)d_in[19];

    float* out_final = (float*)d_out;           // [6144*30*2]
    float* out_conf  = out_final + 368640;      // [6144]
    float* out_ep    = out_conf + 6144;         // [6144*2]

    char* ws = (char*)d_ws;
    size_t off = 0;
    auto alloc = [&](size_t bytes) -> void* {
        void* p = ws + off;
        off += (bytes + 255) & ~(size_t)255;
        return p;
    };
    unsigned short* Whid_b  = (unsigned short*)alloc(65536 * 2);
    unsigned short* Wih0_b  = (unsigned short*)alloc(262144 * 2);
    unsigned short* Whh0_b  = (unsigned short*)alloc(262144 * 2);
    unsigned short* Wcat1_b = (unsigned short*)alloc(524288 * 2);
    unsigned short* comb_b  = (unsigned short*)alloc(1572864 * 2);
    unsigned short* hid_b   = (unsigned short*)alloc(1572864 * 2);
    unsigned short* h0a     = (unsigned short*)alloc(1572864 * 2);
    unsigned short* h0b     = (unsigned short*)alloc(1572864 * 2);
    unsigned short* h1a     = (unsigned short*)alloc(1572864 * 2);
    unsigned short* h1b     = (unsigned short*)alloc(1572864 * 2);
    float* ep_buf = (float*)alloc(12288 * 4);
    float* c0s    = (float*)alloc(1572864 * 4);
    float* c1s    = (float*)alloc(1572864 * 4);
    float* gx0    = (float*)alloc((size_t)6144 * 1024 * 4);

    hipMemsetAsync(h0a, 0, 1572864 * 2, stream);
    hipMemsetAsync(h1a, 0, 1572864 * 2, stream);
    hipMemsetAsync(c0s, 0, 1572864 * 4, stream);
    hipMemsetAsync(c1s, 0, 1572864 * 4, stream);

    cvt_weights<<<4352, 256, 0, stream>>>(W_hid, W_ih0, W_hh0, W_ih1, W_hh1,
                                          Whid_b, Wih0_b, Whh0_b, Wcat1_b);
    build_combined<<<6144, 256, 0, stream>>>(obs, lane, ds, comb_b);
    gemm_hidden<<<96, 256, 0, stream>>>(comb_b, Whid_b, b_hid, hid_b);
    head_kernel<<<24, 256, 0, stream>>>(hid_b, W_ep, b_ep, W_conf, b_conf,
                                        out_conf, out_ep, ep_buf);
    dim3 g2(96, 4);
    gemm_gx0<<<g2, 256, 0, stream>>>(hid_b, Wih0_b, W_ih0, b_ih0, ep_buf, gx0);

    unsigned short *h0p = h0a, *h0q = h0b, *h1p = h1a, *h1q = h1b;
    for (int t = 0; t < TT; t++) {
        lstm_step0<<<g2, 256, 0, stream>>>(h0p, Whh0_b, gx0, b_hh0, c0s, h0q);
        lstm_step1<<<g2, 256, 0, stream>>>(h0q, h1p, Wcat1_b, b_ih1, b_hh1,
                                           W_op, b_op, c1s, h1q, out_final, t);
        unsigned short* tmp;
        tmp = h0p; h0p = h0q; h0q = tmp;
        tmp = h1p; h1p = h1q; h1q = tmp;
    }
    final_proj<<<24, 256, 0, stream>>>(h1p, W_op, b_op, out_final);
}